// Round 6
// baseline (357.711 us; speedup 1.0000x reference)
//
#include <hip/hip_runtime.h>

// S4 layer: B=8, L=4096, D=1024, N=128
// R8 = R7 with gemm2 rebuilt for occupancy/streaming:
//   64x128 tiles (4096 blocks), wave owns a full 16-row strip (acc=32 AGPR),
//   hs panel 16 KB DMA (XOR-swizzled via pre-swizzled source), Cwh direct
//   from L2 (kb loop unroll 1 to cap VGPR), per-wave strip epilogue through
//   an 8.4 KB buf overlaid on the dead panel -> ~17 KB LDS, lb(256,6).
//   Bijective XCD swizzle: 8 xcd x 64 row-panels x 8 col-blocks.
// gemm1 (fused scan_agg), scan_carry, scan_final, prep unchanged from R7.

typedef _Float16 half8 __attribute__((ext_vector_type(8)));
typedef _Float16 half4 __attribute__((ext_vector_type(4)));
typedef float f32x4 __attribute__((ext_vector_type(4)));

#define BDIM 8
#define LDIM 4096
#define DDIM 1024
#define NDIM 128
#define MTOT (BDIM * LDIM)       // 32768
#define CHUNK 32
#define NCHUNK (LDIM / CHUNK)    // 128
#define TOTCHUNK (BDIM * NCHUNK) // 1024

__device__ __forceinline__ void dma16(const void* g, void* l) {
    __builtin_amdgcn_global_load_lds((const __attribute__((address_space(1))) void*)g,
                                     (__attribute__((address_space(3))) void*)l, 16, 0, 0);
}

// ---------------- prep: final_state + convert Bw,Cw to f16 ----------------
__global__ __launch_bounds__(256) void prep(const float* __restrict__ x,
                                            const float* __restrict__ Bw,
                                            const float* __restrict__ Cw,
                                            _Float16* __restrict__ Bwh,
                                            _Float16* __restrict__ Cwh,
                                            float* __restrict__ out) {
    const int blk = blockIdx.x;
    const int t = threadIdx.x;
    if (blk < 128) {
        const int n = blk;
        float s = 0.f;
        const float* br = Bw + n * DDIM;
        for (int b = 0; b < BDIM; ++b) {
            const float* xr = x + ((size_t)b * LDIM + (LDIM - 1)) * DDIM;
            for (int k = t; k < DDIM; k += 256)
                s = fmaf(xr[k], br[k], s);
        }
        __shared__ float red[256];
        red[t] = s;
        __syncthreads();
        for (int off = 128; off > 0; off >>= 1) {
            if (t < off) red[t] += red[t + off];
            __syncthreads();
        }
        if (t == 0) {
            float v = red[0] * 0.125f;
            for (int b = 0; b < BDIM; ++b)
                out[(size_t)MTOT * DDIM + b * NDIM + n] = v;
        }
    } else {
        const int base = (blk - 128) * 4096;
#pragma unroll
        for (int j = 0; j < 4; ++j) {
            int e = base + j * 1024 + t * 4;
            const float* src;
            _Float16* dst;
            if (e < 131072) { src = Bw + e; dst = Bwh + e; }
            else            { src = Cw + (e - 131072); dst = Cwh + (e - 131072); }
            float4 v = *reinterpret_cast<const float4*>(src);
            half4 h = { (_Float16)v.x, (_Float16)v.y, (_Float16)v.z, (_Float16)v.w };
            *reinterpret_cast<half4*>(dst) = h;
        }
    }
}

// ---------------- GEMM1 + fused scan_agg ----------------
// xp[m][n] = sum_k x[m][k]*Bw[n][k]; agg[chunk][n] = scan-aggregate of tile.
// 32x128 tile == one scan chunk. BK=64, 4 waves (2x2 of 16x64), swizzled LDS.
__global__ __launch_bounds__(256, 8) void gemm1(const float* __restrict__ x,
                                                const _Float16* __restrict__ Bwh,
                                                const float* __restrict__ logA,
                                                float* __restrict__ xp,
                                                float* __restrict__ agg) {
    __shared__ _Float16 As[32 * 64];    // 4 KB, swizzled
    __shared__ _Float16 Bs[128 * 64];   // 16 KB, swizzled; reused as f32 tile buf
    const int t = threadIdx.x;
    const int row0 = blockIdx.x * 32;
    const int wave = t >> 6, lane = t & 63;
    const int wr = (wave >> 1) * 16, wc = (wave & 1) * 64;
    const int lrow = lane & 15, kq = (lane >> 4) * 8;
    const int kc = kq >> 3;

    f32x4 acc[4] = {};

    for (int kk = 0; kk < DDIM; kk += 64) {
#pragma unroll
        for (int inst = 0; inst < 4; ++inst) {
            int s = inst * 256 + t;
            int r = s >> 3;
            int cs = (s & 7) ^ (r & 7);
            dma16(&Bwh[(size_t)r * DDIM + kk + cs * 8], &Bs[(inst * 256 + wave * 64) * 8]);
        }
#pragma unroll
        for (int j = 0; j < 2; ++j) {
            int s = t + 256 * j;
            int r = s >> 4, c4 = s & 15;
            float4 v = *reinterpret_cast<const float4*>(&x[(size_t)(row0 + r) * DDIM + kk + c4 * 4]);
            half4 h = { (_Float16)v.x, (_Float16)v.y, (_Float16)v.z, (_Float16)v.w };
            int pc = (c4 >> 1) ^ (r & 7);
            *reinterpret_cast<half4*>(&As[r * 64 + pc * 8 + (c4 & 1) * 4]) = h;
        }
        __syncthreads();

        const int arow = wr + lrow;
#pragma unroll
        for (int ks = 0; ks < 2; ++ks) {
            half8 af = *reinterpret_cast<const half8*>(&As[arow * 64 + ((ks * 4 + kc) ^ (arow & 7)) * 8]);
            half8 bf[4];
#pragma unroll
            for (int ct = 0; ct < 4; ++ct) {
                int brow = wc + ct * 16 + lrow;
                bf[ct] = *reinterpret_cast<const half8*>(&Bs[brow * 64 + ((ks * 4 + kc) ^ (brow & 7)) * 8]);
            }
#pragma unroll
            for (int ct = 0; ct < 4; ++ct)
                acc[ct] = __builtin_amdgcn_mfma_f32_16x16x32_f16(af, bf[ct], acc[ct], 0, 0, 0);
        }
        __syncthreads();
    }

    float* tb = (float*)Bs;             // 32x128 f32 = 16 KB
    const int q4 = (lane >> 4) * 4;
#pragma unroll
    for (int ct = 0; ct < 4; ++ct) {
        int col = wc + ct * 16 + lrow;
#pragma unroll
        for (int i = 0; i < 4; ++i)
            tb[(wr + q4 + i) * NDIM + col] = acc[ct][i];
    }
    __syncthreads();
#pragma unroll
    for (int j = 0; j < 4; ++j) {
        int idx = t + 256 * j;
        int row = idx >> 5, c4 = idx & 31;
        *reinterpret_cast<float4*>(&xp[(size_t)(row0 + row) * NDIM + c4 * 4]) =
            *reinterpret_cast<const float4*>(&tb[row * NDIM + c4 * 4]);
    }
    if (t < 128) {
        const float A = expf(logA[t]);
        float h = 0.f;
#pragma unroll
        for (int j = 0; j < CHUNK; ++j)
            h = fmaf(A, h, tb[j * NDIM + t]);
        agg[(size_t)blockIdx.x * NDIM + t] = h;
    }
}

// ---------------- scan phase 2: carries across chunks ----------------
__global__ void scan_carry(const float* __restrict__ agg, const float* __restrict__ logA,
                           float* __restrict__ hprev) {
    const int idx = blockIdx.x * blockDim.x + threadIdx.x;  // 1024 total
    const int b = idx >> 7, n = idx & 127;
    const float Ac = expf((float)CHUNK * logA[n]);
    float c = 0.f;
#pragma unroll 8
    for (int ch = 0; ch < NCHUNK; ++ch) {
        int g = (b * NCHUNK + ch) * NDIM + n;
        hprev[g] = c;
        c = fmaf(Ac, c, agg[g]);
    }
}

// ---------------- scan phase 3: final scan, write hs (f16) ----------------
__global__ void scan_final(const float* __restrict__ xp, const float* __restrict__ logA,
                           const float* __restrict__ hprev, _Float16* __restrict__ hs) {
    const int chunk = blockIdx.x;
    const int n = threadIdx.x;
    const float A = expf(logA[n]);
    float h = hprev[chunk * NDIM + n];
    const float* u = xp + (size_t)chunk * CHUNK * NDIM + n;
    _Float16* o = hs + (size_t)chunk * CHUNK * NDIM + n;
#pragma unroll
    for (int j = 0; j < CHUNK; ++j) {
        h = fmaf(A, h, u[j * NDIM]);
        o[j * NDIM] = (_Float16)h;
    }
}

// ---------------- GEMM2: y = hs @ Cw^T + x*Dp ----------------
// 64x128 tile (tokens x d), 4096 blocks. Wave w owns the full 16-row strip
// wr=w*16 (acc = 8 x f32x4 = 32 AGPR). hs panel 64x128 f16 (16 KB) DMA-staged,
// XOR-swizzled via pre-swizzled source. Cwh fragments direct from L2
// (kb loop unroll 1 caps live bf regs). Epilogue: per-wave strip through an
// 8.4 KB fp32 buf overlaid on the dead panel -> ~17 KB LDS -> 6 blocks/CU.
// Bijective XCD swizzle: 8 xcd x 64 row-panels x 8 col-blocks (1 MB hs slab/XCD L2).
#define SBUFW 132
__global__ __launch_bounds__(256, 6) void gemm2(const _Float16* __restrict__ hs,
                                                const _Float16* __restrict__ Cwh,
                                                const float* __restrict__ x,
                                                const float* __restrict__ Dp,
                                                float* __restrict__ y) {
    __shared__ __align__(16) _Float16 hsP[64 * 128];   // 16 KB; overlaid by strip buf
    __shared__ __align__(16) float DpS[128];

    const int t = threadIdx.x;
    const int id = blockIdx.x;              // 4096 = 8 xcd * 64 row-panels * 8 col
    const int xb = (id & 7) * 64 + ((id >> 3) & 63);
    const int yb = id >> 9;
    const int row0 = xb * 64;
    const int col0 = yb * 128;
    const int wave = t >> 6, lane = t & 63;
    const int wr = wave * 16;
    const int lrow = lane & 15, kq = (lane >> 4) * 8;

    if (t < 128) DpS[t] = Dp[col0 + t];

    // DMA hs panel: 64x128 f16, 16 chunks/row, source chunk pre-swizzled
#pragma unroll
    for (int inst = 0; inst < 4; ++inst) {
        int s = inst * 256 + t;
        int r = s >> 4, c = s & 15;
        dma16(&hs[(size_t)(row0 + r) * NDIM + ((c ^ (r & 7)) * 8)],
              &hsP[(inst * 256 + wave * 64) * 8]);
    }
    __syncthreads();

    const _Float16* cb = Cwh + (size_t)(col0 + lrow) * NDIM + kq;
    const int ar = wr + lrow;

    f32x4 acc[8] = {};
#pragma unroll 1
    for (int kb = 0; kb < 4; ++kb) {
        int ck = kb * 4 + (kq >> 3);
        half8 af = *reinterpret_cast<const half8*>(&hsP[ar * NDIM + ((ck ^ (ar & 7)) * 8)]);
#pragma unroll
        for (int ct = 0; ct < 8; ++ct) {
            half8 bf = *reinterpret_cast<const half8*>(cb + (size_t)ct * 16 * NDIM + kb * 32);
            acc[ct] = __builtin_amdgcn_mfma_f32_16x16x32_f16(af, bf, acc[ct], 0, 0, 0);
        }
    }

    // epilogue: 4 strips of 16 rows; wave s owns strip s (buf overlays panel)
    float* buf = (float*)hsP;
    const int q4 = (lane >> 4) * 4;
#pragma unroll 1
    for (int s = 0; s < 4; ++s) {
        __syncthreads();
        if (wave == s) {
#pragma unroll
            for (int ct = 0; ct < 8; ++ct) {
                int col = ct * 16 + lrow;
#pragma unroll
                for (int i = 0; i < 4; ++i)
                    buf[(q4 + i) * SBUFW + col] = acc[ct][i];
            }
        }
        __syncthreads();
#pragma unroll
        for (int j = 0; j < 2; ++j) {
            int idx = t + 256 * j;
            int row = idx >> 5, c4 = idx & 31;
            int grow = row0 + s * 16 + row;
            float4 a = *reinterpret_cast<const float4*>(&buf[row * SBUFW + c4 * 4]);
            float4 xv = *reinterpret_cast<const float4*>(&x[(size_t)grow * DDIM + col0 + c4 * 4]);
            float4 dp = *reinterpret_cast<const float4*>(&DpS[c4 * 4]);
            float4 o;
            o.x = a.x + xv.x * dp.x;
            o.y = a.y + xv.y * dp.y;
            o.z = a.z + xv.z * dp.z;
            o.w = a.w + xv.w * dp.w;
            *reinterpret_cast<float4*>(&y[(size_t)grow * DDIM + col0 + c4 * 4]) = o;
        }
    }
}

extern "C" void kernel_launch(void* const* d_in, const int* in_sizes, int n_in,
                              void* d_out, int out_size, void* d_ws, size_t ws_size,
                              hipStream_t stream) {
    const float* x    = (const float*)d_in[0];   // (8, 4096, 1024)
    const float* Bw   = (const float*)d_in[1];   // (128, 1024)
    const float* Cw   = (const float*)d_in[2];   // (1024, 128)
    const float* logA = (const float*)d_in[3];   // (128,)
    const float* Dp   = (const float*)d_in[4];   // (1024,)
    float* out = (float*)d_out;                  // y (33554432) + final_state (1024)

    char* ws = (char*)d_ws;
    float*    xp    = (float*)   (ws);                       // 16,777,216 B
    _Float16* hs    = (_Float16*)(ws + 16777216);            //  8,388,608 B
    float*    agg   = (float*)   (ws + 25165824);            //    524,288 B
    float*    hprev = (float*)   (ws + 25690112);            //    524,288 B
    _Float16* Bwh   = (_Float16*)(ws + 26214400);            //    262,144 B
    _Float16* Cwh   = (_Float16*)(ws + 26476544);            //    262,144 B

    prep<<<192, 256, 0, stream>>>(x, Bw, Cw, Bwh, Cwh, out);
    gemm1<<<MTOT / 32, 256, 0, stream>>>(x, Bwh, logA, xp, agg);
    scan_carry<<<8, 128, 0, stream>>>(agg, logA, hprev);
    scan_final<<<TOTCHUNK, 128, 0, stream>>>(xp, logA, hprev, hs);
    gemm2<<<4096, 256, 0, stream>>>(hs, Cwh, x, Dp, out);
}

// Round 7
// 352.201 us; speedup vs baseline: 1.0156x; 1.0156x over previous
//
#include <hip/hip_runtime.h>

// S4 layer: B=8, L=4096, D=1024, N=128
// R9 = R8 with gemm2 rebuilt for load depth (T14-style):
//   - DMA-stage BOTH hs panel (16 KB f16, XOR-swizzled via pre-swizzled src)
//     AND the x residual tile (32 KB fp32, linear) at kernel entry:
//     12 async global_load_lds per wave, ONE drain barrier.
//   - full-unroll kb loop (16 Cwh L2 loads hoisted by compiler; R8's
//     unroll-1 destroyed this and regressed 80->101).
//   - residual x*Dp added in REGISTERS from LDS; epilogue has no global
//     reads: one transpose pass through per-wave strip bufs overlaid on
//     the dead staging LDS, 2 barriers total, coalesced float4 y stores.
//   - 48 KB LDS -> 3 blocks/CU, launch_bounds(256,3).
// gemm1 (fused scan_agg), scan_carry, scan_final, prep unchanged from R8.

typedef _Float16 half8 __attribute__((ext_vector_type(8)));
typedef _Float16 half4 __attribute__((ext_vector_type(4)));
typedef float f32x4 __attribute__((ext_vector_type(4)));

#define BDIM 8
#define LDIM 4096
#define DDIM 1024
#define NDIM 128
#define MTOT (BDIM * LDIM)       // 32768
#define CHUNK 32
#define NCHUNK (LDIM / CHUNK)    // 128
#define TOTCHUNK (BDIM * NCHUNK) // 1024

__device__ __forceinline__ void dma16(const void* g, void* l) {
    __builtin_amdgcn_global_load_lds((const __attribute__((address_space(1))) void*)g,
                                     (__attribute__((address_space(3))) void*)l, 16, 0, 0);
}

// ---------------- prep: final_state + convert Bw,Cw to f16 ----------------
__global__ __launch_bounds__(256) void prep(const float* __restrict__ x,
                                            const float* __restrict__ Bw,
                                            const float* __restrict__ Cw,
                                            _Float16* __restrict__ Bwh,
                                            _Float16* __restrict__ Cwh,
                                            float* __restrict__ out) {
    const int blk = blockIdx.x;
    const int t = threadIdx.x;
    if (blk < 128) {
        const int n = blk;
        float s = 0.f;
        const float* br = Bw + n * DDIM;
        for (int b = 0; b < BDIM; ++b) {
            const float* xr = x + ((size_t)b * LDIM + (LDIM - 1)) * DDIM;
            for (int k = t; k < DDIM; k += 256)
                s = fmaf(xr[k], br[k], s);
        }
        __shared__ float red[256];
        red[t] = s;
        __syncthreads();
        for (int off = 128; off > 0; off >>= 1) {
            if (t < off) red[t] += red[t + off];
            __syncthreads();
        }
        if (t == 0) {
            float v = red[0] * 0.125f;
            for (int b = 0; b < BDIM; ++b)
                out[(size_t)MTOT * DDIM + b * NDIM + n] = v;
        }
    } else {
        const int base = (blk - 128) * 4096;
#pragma unroll
        for (int j = 0; j < 4; ++j) {
            int e = base + j * 1024 + t * 4;
            const float* src;
            _Float16* dst;
            if (e < 131072) { src = Bw + e; dst = Bwh + e; }
            else            { src = Cw + (e - 131072); dst = Cwh + (e - 131072); }
            float4 v = *reinterpret_cast<const float4*>(src);
            half4 h = { (_Float16)v.x, (_Float16)v.y, (_Float16)v.z, (_Float16)v.w };
            *reinterpret_cast<half4*>(dst) = h;
        }
    }
}

// ---------------- GEMM1 + fused scan_agg ----------------
// xp[m][n] = sum_k x[m][k]*Bw[n][k]; agg[chunk][n] = scan-aggregate of tile.
// 32x128 tile == one scan chunk. BK=64, 4 waves (2x2 of 16x64), swizzled LDS.
__global__ __launch_bounds__(256, 8) void gemm1(const float* __restrict__ x,
                                                const _Float16* __restrict__ Bwh,
                                                const float* __restrict__ logA,
                                                float* __restrict__ xp,
                                                float* __restrict__ agg) {
    __shared__ _Float16 As[32 * 64];    // 4 KB, swizzled
    __shared__ _Float16 Bs[128 * 64];   // 16 KB, swizzled; reused as f32 tile buf
    const int t = threadIdx.x;
    const int row0 = blockIdx.x * 32;
    const int wave = t >> 6, lane = t & 63;
    const int wr = (wave >> 1) * 16, wc = (wave & 1) * 64;
    const int lrow = lane & 15, kq = (lane >> 4) * 8;
    const int kc = kq >> 3;

    f32x4 acc[4] = {};

    for (int kk = 0; kk < DDIM; kk += 64) {
#pragma unroll
        for (int inst = 0; inst < 4; ++inst) {
            int s = inst * 256 + t;
            int r = s >> 3;
            int cs = (s & 7) ^ (r & 7);
            dma16(&Bwh[(size_t)r * DDIM + kk + cs * 8], &Bs[(inst * 256 + wave * 64) * 8]);
        }
#pragma unroll
        for (int j = 0; j < 2; ++j) {
            int s = t + 256 * j;
            int r = s >> 4, c4 = s & 15;
            float4 v = *reinterpret_cast<const float4*>(&x[(size_t)(row0 + r) * DDIM + kk + c4 * 4]);
            half4 h = { (_Float16)v.x, (_Float16)v.y, (_Float16)v.z, (_Float16)v.w };
            int pc = (c4 >> 1) ^ (r & 7);
            *reinterpret_cast<half4*>(&As[r * 64 + pc * 8 + (c4 & 1) * 4]) = h;
        }
        __syncthreads();

        const int arow = wr + lrow;
#pragma unroll
        for (int ks = 0; ks < 2; ++ks) {
            half8 af = *reinterpret_cast<const half8*>(&As[arow * 64 + ((ks * 4 + kc) ^ (arow & 7)) * 8]);
            half8 bf[4];
#pragma unroll
            for (int ct = 0; ct < 4; ++ct) {
                int brow = wc + ct * 16 + lrow;
                bf[ct] = *reinterpret_cast<const half8*>(&Bs[brow * 64 + ((ks * 4 + kc) ^ (brow & 7)) * 8]);
            }
#pragma unroll
            for (int ct = 0; ct < 4; ++ct)
                acc[ct] = __builtin_amdgcn_mfma_f32_16x16x32_f16(af, bf[ct], acc[ct], 0, 0, 0);
        }
        __syncthreads();
    }

    float* tb = (float*)Bs;             // 32x128 f32 = 16 KB
    const int q4 = (lane >> 4) * 4;
#pragma unroll
    for (int ct = 0; ct < 4; ++ct) {
        int col = wc + ct * 16 + lrow;
#pragma unroll
        for (int i = 0; i < 4; ++i)
            tb[(wr + q4 + i) * NDIM + col] = acc[ct][i];
    }
    __syncthreads();
#pragma unroll
    for (int j = 0; j < 4; ++j) {
        int idx = t + 256 * j;
        int row = idx >> 5, c4 = idx & 31;
        *reinterpret_cast<float4*>(&xp[(size_t)(row0 + row) * NDIM + c4 * 4]) =
            *reinterpret_cast<const float4*>(&tb[row * NDIM + c4 * 4]);
    }
    if (t < 128) {
        const float A = expf(logA[t]);
        float h = 0.f;
#pragma unroll
        for (int j = 0; j < CHUNK; ++j)
            h = fmaf(A, h, tb[j * NDIM + t]);
        agg[(size_t)blockIdx.x * NDIM + t] = h;
    }
}

// ---------------- scan phase 2: carries across chunks ----------------
__global__ void scan_carry(const float* __restrict__ agg, const float* __restrict__ logA,
                           float* __restrict__ hprev) {
    const int idx = blockIdx.x * blockDim.x + threadIdx.x;  // 1024 total
    const int b = idx >> 7, n = idx & 127;
    const float Ac = expf((float)CHUNK * logA[n]);
    float c = 0.f;
#pragma unroll 8
    for (int ch = 0; ch < NCHUNK; ++ch) {
        int g = (b * NCHUNK + ch) * NDIM + n;
        hprev[g] = c;
        c = fmaf(Ac, c, agg[g]);
    }
}

// ---------------- scan phase 3: final scan, write hs (f16) ----------------
__global__ void scan_final(const float* __restrict__ xp, const float* __restrict__ logA,
                           const float* __restrict__ hprev, _Float16* __restrict__ hs) {
    const int chunk = blockIdx.x;
    const int n = threadIdx.x;
    const float A = expf(logA[n]);
    float h = hprev[chunk * NDIM + n];
    const float* u = xp + (size_t)chunk * CHUNK * NDIM + n;
    _Float16* o = hs + (size_t)chunk * CHUNK * NDIM + n;
#pragma unroll
    for (int j = 0; j < CHUNK; ++j) {
        h = fmaf(A, h, u[j * NDIM]);
        o[j * NDIM] = (_Float16)h;
    }
}

// ---------------- GEMM2: y = hs @ Cw^T + x*Dp ----------------
// 64x128 tile (tokens x d), 4096 blocks, bijective XCD swizzle.
// Stage at entry via async DMA (one drain): hs panel 16 KB f16 (swizzled
// source) + x tile 32 KB fp32 (linear). Full-unroll compute (Cwh loads
// hoisted). Residual added in regs from LDS; epilogue = one transpose
// through per-wave strip bufs overlaid on dead staging LDS + coalesced
// float4 stores. 48 KB LDS -> 3 blocks/CU.
__global__ __launch_bounds__(256, 3) void gemm2(const _Float16* __restrict__ hs,
                                                const _Float16* __restrict__ Cwh,
                                                const float* __restrict__ x,
                                                const float* __restrict__ Dp,
                                                float* __restrict__ y) {
    __shared__ __align__(16) char smem[49152];
    _Float16* hsP = (_Float16*)smem;            // [64][128] f16, 16 KB, swizzled
    float* xS = (float*)(smem + 16384);         // [64][128] f32, 32 KB, linear

    const int t = threadIdx.x;
    const int id = blockIdx.x;              // 4096 = 8 xcd * 64 row-panels * 8 col
    const int xb = (id & 7) * 64 + ((id >> 3) & 63);
    const int yb = id >> 9;
    const int row0 = xb * 64;
    const int col0 = yb * 128;
    const int wave = t >> 6, lane = t & 63;
    const int wr = wave * 16;
    const int lrow = lane & 15, kq = (lane >> 4) * 8;

    // DMA hs panel: 64x128 f16, source chunk pre-swizzled (read swizzles back)
#pragma unroll
    for (int inst = 0; inst < 4; ++inst) {
        int s = inst * 256 + t;
        int r = s >> 4, c = s & 15;
        dma16(&hs[(size_t)(row0 + r) * NDIM + ((c ^ (r & 7)) * 8)],
              &hsP[(inst * 256 + wave * 64) * 8]);
    }
    // DMA x tile: 64 rows x 512 B; one wave-inst = 1 KB = 2 rows
#pragma unroll
    for (int inst = 0; inst < 8; ++inst) {
        int slab = wave * 8 + inst;                        // 0..31
        int r = slab * 2 + (lane >> 5);
        int c = lane & 31;
        dma16(&x[(size_t)(row0 + r) * DDIM + col0 + c * 4], &xS[slab * 256]);
    }
    __syncthreads();

    const _Float16* cb = Cwh + (size_t)(col0 + lrow) * NDIM + kq;
    const int ar = wr + lrow;

    f32x4 acc[8] = {};
#pragma unroll
    for (int kb = 0; kb < 4; ++kb) {
        int ck = kb * 4 + (kq >> 3);
        half8 af = *reinterpret_cast<const half8*>(&hsP[ar * NDIM + ((ck ^ (ar & 7)) * 8)]);
#pragma unroll
        for (int ct = 0; ct < 8; ++ct) {
            half8 bf = *reinterpret_cast<const half8*>(cb + (size_t)ct * 16 * NDIM + kb * 32);
            acc[ct] = __builtin_amdgcn_mfma_f32_16x16x32_f16(af, bf, acc[ct], 0, 0, 0);
        }
    }

    // residual in registers: acc += x * Dp (xS rows of THIS wave's strip)
    const int q4 = (lane >> 4) * 4;
    float dp[8];
#pragma unroll
    for (int ct = 0; ct < 8; ++ct) dp[ct] = Dp[col0 + ct * 16 + lrow];
#pragma unroll
    for (int ct = 0; ct < 8; ++ct)
#pragma unroll
        for (int i = 0; i < 4; ++i)
            acc[ct][i] = fmaf(xS[(wr + q4 + i) * NDIM + ct * 16 + lrow], dp[ct], acc[ct][i]);

    // epilogue: per-wave [16][132] strip bufs overlaid on dead staging LDS
    __syncthreads();
    float* buf = (float*)smem;                  // 4 x 2112 floats = 33792 B
#pragma unroll
    for (int ct = 0; ct < 8; ++ct)
#pragma unroll
        for (int i = 0; i < 4; ++i)
            buf[wave * 2112 + (q4 + i) * 132 + ct * 16 + lrow] = acc[ct][i];
    __syncthreads();
#pragma unroll
    for (int j = 0; j < 8; ++j) {
        int idx = t + 256 * j;
        int row = idx >> 5, c4 = idx & 31;
        float4 v = *reinterpret_cast<const float4*>(
            &buf[(row >> 4) * 2112 + (row & 15) * 132 + c4 * 4]);
        *reinterpret_cast<float4*>(&y[(size_t)(row0 + row) * DDIM + col0 + c4 * 4]) = v;
    }
}

extern "C" void kernel_launch(void* const* d_in, const int* in_sizes, int n_in,
                              void* d_out, int out_size, void* d_ws, size_t ws_size,
                              hipStream_t stream) {
    const float* x    = (const float*)d_in[0];   // (8, 4096, 1024)
    const float* Bw   = (const float*)d_in[1];   // (128, 1024)
    const float* Cw   = (const float*)d_in[2];   // (1024, 128)
    const float* logA = (const float*)d_in[3];   // (128,)
    const float* Dp   = (const float*)d_in[4];   // (1024,)
    float* out = (float*)d_out;                  // y (33554432) + final_state (1024)

    char* ws = (char*)d_ws;
    float*    xp    = (float*)   (ws);                       // 16,777,216 B
    _Float16* hs    = (_Float16*)(ws + 16777216);            //  8,388,608 B
    float*    agg   = (float*)   (ws + 25165824);            //    524,288 B
    float*    hprev = (float*)   (ws + 25690112);            //    524,288 B
    _Float16* Bwh   = (_Float16*)(ws + 26214400);            //    262,144 B
    _Float16* Cwh   = (_Float16*)(ws + 26476544);            //    262,144 B

    prep<<<192, 256, 0, stream>>>(x, Bw, Cw, Bwh, Cwh, out);
    gemm1<<<MTOT / 32, 256, 0, stream>>>(x, Bwh, logA, xp, agg);
    scan_carry<<<8, 128, 0, stream>>>(agg, logA, hprev);
    scan_final<<<TOTCHUNK, 128, 0, stream>>>(xp, logA, hprev, hs);
    gemm2<<<4096, 256, 0, stream>>>(hs, Cwh, x, Dp, out);
}